// Round 10
// baseline (218215.771 us; speedup 1.0000x reference)
//
#include <hip/hip_runtime.h>
#include <math.h>

// ============================================================================
// LARNN forward, MI355X — persistent kernel, fence-free sc1 (round-7 skeleton).
// ALL-F32 (bf16 diverges — chaotic recurrence). Deterministic BN stats.
// Round 10 = round 7 EXACTLY, except the GEMM inner loop:
//   - ALL A-slabs preloaded to registers upfront (full unroll, const indices)
//   - B prefetched 1 slab ahead as SSA registers (no rotating arrays!)
//   - fully-unrolled slab loop (round-9's unroll-1 rotation spilled to
//     scratch: WRITE_SIZE 2.1GB->188GB was the spill fingerprint)
// ============================================================================

#define T_  128
#define B_  256
#define F_  128
#define H_  512
#define W_  16
#define H4_ 2048
#define EPS_ 1e-5f
#define BH_ (B_*H_)
#define NBLK 256
#define NTHR 512
#define FSTRIDE 32   // uints per flag (128B line)

typedef __attribute__((ext_vector_type(4))) float f4;
typedef __attribute__((ext_vector_type(2))) float f2;
typedef unsigned long long u64;

__device__ __forceinline__ float eluf(float x){ return x > 0.f ? x : expf(x) - 1.f; }
__device__ __forceinline__ float sigf(float x){ return 1.f / (1.f + expf(-x)); }

// ---- LLC-coherent (sc1) relaxed accessors: no cache maintenance emitted ----
__device__ __forceinline__ f4 ld_c(const float* p) {
  union { f4 v; u64 q[2]; } u;
  u.q[0] = __hip_atomic_load((const u64*)p,     __ATOMIC_RELAXED, __HIP_MEMORY_SCOPE_AGENT);
  u.q[1] = __hip_atomic_load((const u64*)p + 1, __ATOMIC_RELAXED, __HIP_MEMORY_SCOPE_AGENT);
  return u.v;
}
__device__ __forceinline__ void st_c(float* p, f4 v) {
  union { f4 v; u64 q[2]; } u; u.v = v;
  __hip_atomic_store((u64*)p,     u.q[0], __ATOMIC_RELAXED, __HIP_MEMORY_SCOPE_AGENT);
  __hip_atomic_store((u64*)p + 1, u.q[1], __ATOMIC_RELAXED, __HIP_MEMORY_SCOPE_AGENT);
}
__device__ __forceinline__ float ldf_c(const float* p) {
  unsigned u = __hip_atomic_load((const unsigned*)p, __ATOMIC_RELAXED, __HIP_MEMORY_SCOPE_AGENT);
  return __uint_as_float(u);
}
__device__ __forceinline__ void stf_c(float* p, float v) {
  __hip_atomic_store((unsigned*)p, __float_as_uint(v), __ATOMIC_RELAXED, __HIP_MEMORY_SCOPE_AGENT);
}

struct Params {
  const float *x, *W_ih, *b_ih, *W_hh, *Wq_in, *bq_in, *Wq, *bq, *Wk, *bk,
              *Wv, *bv, *Wo, *bo, *W_ac, *b_ac, *g_att, *be_att, *g_post, *be_post;
  float *out, *c, *q, *Qh, *ctx, *attp, *hv, *pre, *Kbuf, *Vbuf, *stA, *stP;
  unsigned *gen, *arr;
};

// Round-7 barrier: flag store + block-0 parallel aggregation + gen release.
__device__ __forceinline__ void gbar(unsigned* arr, unsigned* gen, unsigned g) {
  asm volatile("s_waitcnt vmcnt(0) lgkmcnt(0)" ::: "memory");
  __syncthreads();
  const int tid = threadIdx.x;
  if (tid == 0)
    __hip_atomic_store(&arr[blockIdx.x * FSTRIDE], g, __ATOMIC_RELAXED, __HIP_MEMORY_SCOPE_AGENT);
  if (blockIdx.x == 0) {
    if (tid < NBLK) {
      while (__hip_atomic_load(&arr[tid * FSTRIDE], __ATOMIC_RELAXED, __HIP_MEMORY_SCOPE_AGENT) < g)
        __builtin_amdgcn_s_sleep(1);
    }
    __syncthreads();
    if (tid == 0)
      __hip_atomic_store(gen, g, __ATOMIC_RELAXED, __HIP_MEMORY_SCOPE_AGENT);
  } else {
    if (tid == 0) {
      while (__hip_atomic_load(gen, __ATOMIC_RELAXED, __HIP_MEMORY_SCOPE_AGENT) < g)
        __builtin_amdgcn_s_sleep(1);
    }
  }
  __syncthreads();
}

// BN scale/shift from single-partial stats stP[2][512] (gates output).
__device__ __forceinline__ void prepP(const float* stP, const float* gn, const float* be,
                                      float* scl, float* shf, int tid) {
  if (tid < H_) {
    float S  = ldf_c(stP + tid);
    float S2 = ldf_c(stP + H_ + tid);
    float mu  = S * (1.f / B_);
    float var = S2 * (1.f / B_) - mu * mu;
    float sc  = rsqrtf(var + EPS_) * gn[tid];
    scl[tid] = sc; shf[tid] = be[tid] - mu * sc;
  }
}

// BN scale/shift from 4-way partial stats stA[4][2][512] (Wo GEMM output).
__device__ __forceinline__ void prepA(const float* stA, const float* gn, const float* be,
                                      float* scl, float* shf, int tid) {
  if (tid < H_) {
    float S  = ldf_c(stA + tid) + ldf_c(stA + 1024 + tid) + ldf_c(stA + 2048 + tid) + ldf_c(stA + 3072 + tid);
    float S2 = ldf_c(stA + 512 + tid) + ldf_c(stA + 1536 + tid) + ldf_c(stA + 2560 + tid) + ldf_c(stA + 3584 + tid);
    float mu  = S * (1.f / B_);
    float var = S2 * (1.f / B_) - mu * mu;
    float sc  = rsqrtf(var + EPS_) * gn[tid];
    scl[tid] = sc; shf[tid] = be[tid] - mu * sc;
  }
}

// ---------------------------------------------------------------------------
// 64x64 output tile, 512 threads, 2x4 microtile (round-7 layout).
// Seg1: K = NS1*32 (A plain or sc1). Seg2 (optional, useA2): K = NS2*32,
// A always sc1 (hv), optionally normalized. All A preloaded to registers.
// B prefetched 1 slab ahead (SSA regs). Two syncthreads per slab.
// ---------------------------------------------------------------------------
struct GJ {
  const float* A1; int lda1; int sc1_1; int nrm1;
  const float* A2; int lda2; int nrm2; int useA2;
  const float* W1; const float* W2;    // [K][N] row-major, stride N (plain)
  const float* b1; const float* b2; const float* addm;
  float* out; float* stats; int mIdx;
  int N; int m0; int n0; int doElu;
};

template<int NS1, int NS2>
__device__ void gemm_tile(const GJ& J, int tid,
                          float (*As)[36], float (*Bs)[68],
                          const float* scl, const float* shf) {
  const int arow = tid >> 3, akq = (tid & 7) * 4;
  const int bkk = tid >> 4, bnn = (tid & 15) * 4;
  const int ty = tid >> 4, tx = tid & 15;
  constexpr int NT = NS1 + NS2;

  // ---- preload all A slabs (full unroll, constant indices) ----
  f4 ar1[NS1];
  f4 ar2[NS2 > 0 ? NS2 : 1];
  {
    const float* a1 = J.A1 + (size_t)(J.m0 + arow) * J.lda1 + akq;
    if (J.sc1_1) {
      #pragma unroll
      for (int s = 0; s < NS1; ++s) ar1[s] = ld_c(a1 + s * 32);
    } else {
      #pragma unroll
      for (int s = 0; s < NS1; ++s) ar1[s] = *(const f4*)(a1 + s * 32);
    }
  }
  if (NS2 > 0 && J.useA2) {
    const float* a2 = J.A2 + (size_t)(J.m0 + arow) * J.lda2 + akq;
    #pragma unroll
    for (int s = 0; s < NS2; ++s) ar2[s] = ld_c(a2 + s * 32);
  }
  f4 am0 = {0.f,0.f,0.f,0.f}, am1 = {0.f,0.f,0.f,0.f};
  if (J.addm) {
    am0 = ld_c(J.addm + (size_t)(J.m0 + ty * 2)     * J.N + J.n0 + tx * 4);
    am1 = ld_c(J.addm + (size_t)(J.m0 + ty * 2 + 1) * J.N + J.n0 + tx * 4);
  }

  const float* w1 = J.W1 + (size_t)bkk * J.N + J.n0 + bnn;
  const float* w2 = (NS2 > 0) ? (J.W2 + (size_t)bkk * J.N + J.n0 + bnn) : w1;
  const size_t wSlab = (size_t)32 * J.N;

  float acc[2][4] = {{0.f,0.f,0.f,0.f},{0.f,0.f,0.f,0.f}};
  f4 brc = *(const f4*)w1;    // B slab 0 (NS1 >= 1 always)

  #pragma unroll
  for (int s = 0; s < NT; ++s) {
    if (s >= NS1 && !J.useA2) break;    // block-uniform; trailing slabs only
    // prefetch next B slab (SSA value)
    f4 brn = brc;
    if (s + 1 < NT) {
      const float* wn = (s + 1 >= NS1) ? (w2 + (size_t)(s + 1 - NS1) * wSlab)
                                       : (w1 + (size_t)(s + 1) * wSlab);
      brn = *(const f4*)wn;
    }
    __syncthreads();   // previous compute done before we overwrite LDS
    {
      f4 v = (s >= NS1) ? ar2[(s >= NS1) ? (s - NS1) : 0] : ar1[(s < NS1) ? s : 0];
      const int nrm = (s >= NS1) ? J.nrm2 : J.nrm1;
      const int sl = (s >= NS1) ? (s - NS1) : s;
      if (nrm) {
        #pragma unroll
        for (int i = 0; i < 4; ++i) {
          int gk = sl * 32 + akq + i;
          v[i] = v[i] * scl[gk] + shf[gk];
        }
      }
      *(f4*)&As[arow][akq] = v;
      *(f4*)&Bs[bkk][bnn] = brc;
    }
    __syncthreads();
    #pragma unroll
    for (int k = 0; k < 32; k += 2) {
      f2 a0 = *(const f2*)&As[ty * 2][k];
      f2 a1 = *(const f2*)&As[ty * 2 + 1][k];
      f4 b0 = *(const f4*)&Bs[k][tx * 4];
      f4 b1 = *(const f4*)&Bs[k + 1][tx * 4];
      #pragma unroll
      for (int j = 0; j < 4; ++j) {
        acc[0][j] = fmaf(a0[0], b0[j], acc[0][j]);
        acc[0][j] = fmaf(a0[1], b1[j], acc[0][j]);
        acc[1][j] = fmaf(a1[0], b0[j], acc[1][j]);
        acc[1][j] = fmaf(a1[1], b1[j], acc[1][j]);
      }
    }
    brc = brn;
  }

  const int r0 = J.m0 + ty * 2, c0 = J.n0 + tx * 4;
  f4 bias = {0.f, 0.f, 0.f, 0.f};
  if (J.b1) bias += *(const f4*)(J.b1 + c0);
  if (J.b2) bias += *(const f4*)(J.b2 + c0);
  f4 v0, v1;
  #pragma unroll
  for (int j = 0; j < 4; ++j) { v0[j] = acc[0][j] + bias[j]; v1[j] = acc[1][j] + bias[j]; }
  if (J.addm) { v0 += am0; v1 += am1; }
  if (J.doElu) {
    #pragma unroll
    for (int j = 0; j < 4; ++j) { v0[j] = eluf(v0[j]); v1[j] = eluf(v1[j]); }
  }
  st_c(J.out + (size_t)r0 * J.N + c0, v0);
  st_c(J.out + (size_t)(r0 + 1) * J.N + c0, v1);

  if (J.stats) {   // deterministic per-64-row-tile column partials
    float* Af = (float*)As;
    float* Bf = (float*)Bs;
    __syncthreads();
    #pragma unroll
    for (int j = 0; j < 4; ++j) {
      Af[ty * 64 + tx * 4 + j] = v0[j] + v1[j];
      Bf[ty * 64 + tx * 4 + j] = v0[j] * v0[j] + v1[j] * v1[j];
    }
    __syncthreads();
    if (tid < 64) {
      float S = 0.f, S2 = 0.f;
      #pragma unroll
      for (int y = 0; y < 32; ++y) { S += Af[y * 64 + tid]; S2 += Bf[y * 64 + tid]; }
      stf_c(J.stats + J.mIdx * 1024 + J.n0 + tid, S);
      stf_c(J.stats + J.mIdx * 1024 + 512 + J.n0 + tid, S2);
    }
  }
}

__global__ __launch_bounds__(NTHR, 1) void larnn(Params P) {
  __shared__ float As[64][36];
  __shared__ float Bs[32][68];
  __shared__ float scl[H_], shf[H_];
  __shared__ float Qs[H_];
  __shared__ float sc_[8][16], aw_[8][16];

  const int bid = blockIdx.x, tid = threadIdx.x;
  unsigned g = 0;

  for (int t = 0; t < T_; ++t) {
    const float* xt = P.x + (size_t)t * B_ * F_;
    const int slot = (t - 1) & 15;

    // =========== P1: q | K-ring | V-ring | preA | out[t-1] ===========
    if (bid < 32) {
      if (t > 0) prepP(P.stP, P.g_post, P.be_post, scl, shf, tid);
      GJ J = {}; J.A1 = xt; J.lda1 = F_; J.sc1_1 = 0;
      J.A2 = P.hv; J.lda2 = H_; J.nrm2 = 1; J.useA2 = (t > 0);
      J.W1 = P.Wq_in; J.W2 = P.Wq_in + (size_t)F_ * H_;
      J.b1 = P.bq_in; J.out = P.q; J.N = H_;
      J.m0 = (bid >> 3) * 64; J.n0 = (bid & 7) * 64; J.doElu = 1;
      gemm_tile<4, 16>(J, tid, As, Bs, scl, shf);
    } else if (bid < 64) {
      int l = bid - 32;
      GJ J = {}; J.A1 = P.c; J.lda1 = H_; J.sc1_1 = 1;
      J.W1 = P.Wk; J.b1 = P.bk; J.out = P.Kbuf + (size_t)slot * BH_; J.N = H_;
      J.m0 = (l >> 3) * 64; J.n0 = (l & 7) * 64; J.doElu = 1;
      gemm_tile<16, 0>(J, tid, As, Bs, scl, shf);
    } else if (bid < 96) {
      int l = bid - 64;
      GJ J = {}; J.A1 = P.c; J.lda1 = H_; J.sc1_1 = 1;
      J.W1 = P.Wv; J.b1 = P.bv; J.out = P.Vbuf + (size_t)slot * BH_; J.N = H_;
      J.m0 = (l >> 3) * 64; J.n0 = (l & 7) * 64; J.doElu = 1;
      gemm_tile<16, 0>(J, tid, As, Bs, scl, shf);
    } else if (bid < 224) {
      if (t > 0) prepP(P.stP, P.g_post, P.be_post, scl, shf, tid);
      const int ix = bid - 96;
      GJ J = {}; J.A1 = xt; J.lda1 = F_; J.sc1_1 = 0;
      J.A2 = P.hv; J.lda2 = H_; J.nrm2 = 1; J.useA2 = (t > 0);
      J.W1 = P.W_ih; J.W2 = P.W_hh;
      J.b1 = P.b_ih; J.b2 = P.b_ac; J.out = P.pre; J.N = H4_;
      J.m0 = (ix >> 5) * 64; J.n0 = (ix & 31) * 64;
      gemm_tile<4, 16>(J, tid, As, Bs, scl, shf);
    } else if (t > 0) {
      prepP(P.stP, P.g_post, P.be_post, scl, shf, tid);
      __syncthreads();
      const int rb0 = (bid - 224) * 8;
      for (int idx = tid; idx < 1024; idx += NTHR) {
        int r = rb0 + (idx >> 7), cc = (idx & 127) * 4;
        f4 hvv = ld_c(P.hv + (size_t)r * H_ + cc);
        f4 v;
        #pragma unroll
        for (int i = 0; i < 4; ++i) v[i] = hvv[i] * scl[cc + i] + shf[cc + i];
        *(f4*)(P.out + (size_t)(t - 1) * BH_ + (size_t)r * H_ + cc) = v;
      }
    }
    gbar(P.arr, P.gen, ++g);

    // =========== P2: Qh = q@Wq + bq ===========
    if (bid < 32) {
      GJ J = {}; J.A1 = P.q; J.lda1 = H_; J.sc1_1 = 1;
      J.W1 = P.Wq; J.b1 = P.bq; J.out = P.Qh; J.N = H_;
      J.m0 = (bid >> 3) * 64; J.n0 = (bid & 7) * 64;
      gemm_tile<16, 0>(J, tid, As, Bs, scl, shf);
    }
    gbar(P.arr, P.gen, ++g);

    // =========== P3: attention (1 batch row / block) ===========
    {
      const int b = bid;
      const int nv = (t + 1 < W_) ? t + 1 : W_;
      if (tid < 128) *(f4*)&Qs[tid * 4] = ld_c(P.Qh + (size_t)b * H_ + tid * 4);
      __syncthreads();
      {
        const int p = tid >> 2, l4 = tid & 3;
        const int hh = p >> 4, w = p & 15;
        if (w < nv) {
          const int sl = (t - 1 - w) & 15;
          const float* kp = P.Kbuf + ((size_t)sl * B_ + b) * H_ + hh * 64 + l4 * 16;
          const float* qp = Qs + hh * 64 + l4 * 16;
          float s = 0.f;
          #pragma unroll
          for (int d = 0; d < 16; d += 4) {
            f4 kv = ld_c(kp + d);
            f4 qv = *(const f4*)(qp + d);
            s = fmaf(kv[0], qv[0], fmaf(kv[1], qv[1], fmaf(kv[2], qv[2], fmaf(kv[3], qv[3], s))));
          }
          s += __shfl_xor(s, 1); s += __shfl_xor(s, 2);
          if (l4 == 0) sc_[hh][w] = s * 0.125f;
        }
      }
      __syncthreads();
      if (tid < 8) {
        float mx = -1e30f;
        for (int w = 0; w < nv; ++w) mx = fmaxf(mx, sc_[tid][w]);
        float ss = 0.f;
        for (int w = 0; w < nv; ++w) { float e = expf(sc_[tid][w] - mx); aw_[tid][w] = e; ss += e; }
        float inv = 1.f / ss;
        for (int w = 0; w < nv; ++w) aw_[tid][w] *= inv;
      }
      __syncthreads();
      {
        const int j = tid, hh = j >> 6;
        float o = 0.f;
        for (int w = 0; w < nv; ++w) {
          const int sl = (t - 1 - w) & 15;
          o = fmaf(aw_[hh][w], ldf_c(P.Vbuf + ((size_t)sl * B_ + b) * H_ + j), o);
        }
        stf_c(P.ctx + (size_t)b * H_ + j, o);
      }
    }
    gbar(P.arr, P.gen, ++g);

    // =========== P4: attp = elu(ctx@Wo + bo) + BN partials ===========
    if (bid < 32) {
      GJ J = {}; J.A1 = P.ctx; J.lda1 = H_; J.sc1_1 = 1;
      J.W1 = P.Wo; J.b1 = P.bo; J.doElu = 1;
      J.out = P.attp; J.stats = P.stA; J.N = H_;
      J.m0 = (bid >> 3) * 64; J.n0 = (bid & 7) * 64; J.mIdx = J.m0 >> 6;
      gemm_tile<16, 0>(J, tid, As, Bs, scl, shf);
    }
    gbar(P.arr, P.gen, ++g);

    // =========== P5: pre += BN(attp)@W_ac ===========
    if (bid < 128) {
      prepA(P.stA, P.g_att, P.be_att, scl, shf, tid);
      __syncthreads();
      GJ J = {}; J.A1 = P.attp; J.lda1 = H_; J.sc1_1 = 1; J.nrm1 = 1;
      J.W1 = P.W_ac; J.addm = P.pre; J.out = P.pre; J.N = H4_;
      J.m0 = (bid >> 5) * 64; J.n0 = (bid & 31) * 64;
      gemm_tile<16, 0>(J, tid, As, Bs, scl, shf);
    }
    gbar(P.arr, P.gen, ++g);

    // =========== P6: gates + c/hv + BN-post stats ===========
    if (bid < 64) {
      f4* rS = (f4*)As;   // 512 f4 = 8KB scratch (As = 9216B)
      f4* rQ = (f4*)Bs;   // (Bs = 8704B)
      const int sub = tid & 1, r = tid >> 1;
      const int c4 = bid * 8 + sub * 4;
      const size_t rb = (size_t)r * H4_;
      f4 p0 = ld_c(P.pre + rb + c4);
      f4 pf = ld_c(P.pre + rb + c4 + 512);
      f4 pi = ld_c(P.pre + rb + c4 + 1024);
      f4 po = ld_c(P.pre + rb + c4 + 1536);
      const size_t ci = (size_t)r * H_ + c4;
      f4 cold = ld_c(P.c + ci);
      f4 cn, hvv;
      #pragma unroll
      for (int i = 0; i < 4; ++i) {
        float iv = tanhf(p0[i]);
        float fg = sigf(pf[i]), ig = sigf(pi[i]), og = sigf(po[i]);
        cn[i] = iv * ig + cold[i] * fg;
        hvv[i] = og * eluf(cn[i]);
      }
      st_c(P.c + ci, cn);
      st_c(P.hv + ci, hvv);
      rS[sub * 256 + r] = hvv;
      rQ[sub * 256 + r] = hvv * hvv;
      __syncthreads();
      for (int s2 = 128; s2 > 0; s2 >>= 1) {
        if (r < s2) {
          rS[sub * 256 + r] += rS[sub * 256 + r + s2];
          rQ[sub * 256 + r] += rQ[sub * 256 + r + s2];
        }
        __syncthreads();
      }
      if (r == 0) {
        f4 S = rS[sub * 256], Q2 = rQ[sub * 256];
        #pragma unroll
        for (int i = 0; i < 4; ++i) { stf_c(P.stP + c4 + i, S[i]); stf_c(P.stP + 512 + c4 + i, Q2[i]); }
      }
    }
    gbar(P.arr, P.gen, ++g);
  }

  // =========== final out-copy for t = 127 ===========
  if (bid >= 224) {
    prepP(P.stP, P.g_post, P.be_post, scl, shf, tid);
    __syncthreads();
    const int rb0 = (bid - 224) * 8;
    for (int idx = tid; idx < 1024; idx += NTHR) {
      int r = rb0 + (idx >> 7), cc = (idx & 127) * 4;
      f4 hvv = ld_c(P.hv + (size_t)r * H_ + cc);
      f4 v;
      #pragma unroll
      for (int i = 0; i < 4; ++i) v[i] = hvv[i] * scl[cc + i] + shf[cc + i];
      *(f4*)(P.out + (size_t)127 * BH_ + (size_t)r * H_ + cc) = v;
    }
  }
}

#define SYNC_UINTS (32 + NBLK * FSTRIDE)   // gen line + 256 padded flags

__global__ __launch_bounds__(256) void pinit(float* c, unsigned* sync) {
  const int i = blockIdx.x * 256 + threadIdx.x;
  if (i < BH_) c[i] = 0.f;
  if (i < SYNC_UINTS) sync[i] = 0u;
}

extern "C" void kernel_launch(void* const* d_in, const int* in_sizes, int n_in,
                              void* d_out, int out_size, void* d_ws, size_t ws_size,
                              hipStream_t stream) {
  Params P;
  P.x      = (const float*)d_in[0];
  P.W_ih   = (const float*)d_in[1];
  P.b_ih   = (const float*)d_in[2];
  P.W_hh   = (const float*)d_in[3];
  P.Wq_in  = (const float*)d_in[4];
  P.bq_in  = (const float*)d_in[5];
  P.Wq     = (const float*)d_in[6];
  P.bq     = (const float*)d_in[7];
  P.Wk     = (const float*)d_in[8];
  P.bk     = (const float*)d_in[9];
  P.Wv     = (const float*)d_in[10];
  P.bv     = (const float*)d_in[11];
  P.Wo     = (const float*)d_in[12];
  P.bo     = (const float*)d_in[13];
  P.W_ac   = (const float*)d_in[14];
  P.b_ac   = (const float*)d_in[15];
  P.g_att  = (const float*)d_in[16];
  P.be_att = (const float*)d_in[17];
  P.g_post = (const float*)d_in[18];
  P.be_post= (const float*)d_in[19];
  P.out    = (float*)d_out;

  unsigned* sync = (unsigned*)d_ws;
  P.gen = sync;                    // own 128B line
  P.arr = sync + 32;               // 256 flags, 128B stride
  float* fb = (float*)d_ws + SYNC_UINTS;
  P.c    = fb;                 fb += BH_;
  P.q    = fb;                 fb += BH_;
  P.Qh   = fb;                 fb += BH_;
  P.ctx  = fb;                 fb += BH_;
  P.attp = fb;                 fb += BH_;
  P.hv   = fb;                 fb += BH_;
  P.pre  = fb;                 fb += (size_t)B_ * H4_;
  P.Kbuf = fb;                 fb += (size_t)W_ * BH_;
  P.Vbuf = fb;                 fb += (size_t)W_ * BH_;
  P.stA  = fb;                 fb += 4096;
  P.stP  = fb;                 fb += 1024;

  pinit<<<(BH_ + 255) / 256, 256, 0, stream>>>(P.c, sync);
  larnn<<<NBLK, NTHR, 0, stream>>>(P);
}

// Round 11
// 16060.329 us; speedup vs baseline: 13.5873x; 13.5873x over previous
//
#include <hip/hip_runtime.h>
#include <math.h>

// ============================================================================
// LARNN forward, MI355X — persistent kernel, fence-free sc1 (round-7 skeleton,
// verified 18.0 ms). ALL-F32 (bf16 diverges — chaotic recurrence). Det. BN.
// Round 11 = round 7 EXACTLY, except gemm_tile:
//   - LDS double-buffered, ONE __syncthreads per 32-k slab
//   - prefetch as NAMED SCALAR f4 values only (aN1,aN2,bN1) — register
//     ARRAYS carried across the K-loop spill to scratch (rounds 9/10:
//     WRITE_SIZE 2GB->184GB, the spill fingerprint; rule: no arrays).
// ============================================================================

#define T_  128
#define B_  256
#define F_  128
#define H_  512
#define W_  16
#define H4_ 2048
#define EPS_ 1e-5f
#define BH_ (B_*H_)
#define NBLK 256
#define NTHR 512
#define FSTRIDE 32   // uints per flag (128B line)

typedef __attribute__((ext_vector_type(4))) float f4;
typedef __attribute__((ext_vector_type(2))) float f2;
typedef unsigned long long u64;

__device__ __forceinline__ float eluf(float x){ return x > 0.f ? x : expf(x) - 1.f; }
__device__ __forceinline__ float sigf(float x){ return 1.f / (1.f + expf(-x)); }

// ---- LLC-coherent (sc1) relaxed accessors: no cache maintenance emitted ----
__device__ __forceinline__ f4 ld_c(const float* p) {
  union { f4 v; u64 q[2]; } u;
  u.q[0] = __hip_atomic_load((const u64*)p,     __ATOMIC_RELAXED, __HIP_MEMORY_SCOPE_AGENT);
  u.q[1] = __hip_atomic_load((const u64*)p + 1, __ATOMIC_RELAXED, __HIP_MEMORY_SCOPE_AGENT);
  return u.v;
}
__device__ __forceinline__ void st_c(float* p, f4 v) {
  union { f4 v; u64 q[2]; } u; u.v = v;
  __hip_atomic_store((u64*)p,     u.q[0], __ATOMIC_RELAXED, __HIP_MEMORY_SCOPE_AGENT);
  __hip_atomic_store((u64*)p + 1, u.q[1], __ATOMIC_RELAXED, __HIP_MEMORY_SCOPE_AGENT);
}
__device__ __forceinline__ float ldf_c(const float* p) {
  unsigned u = __hip_atomic_load((const unsigned*)p, __ATOMIC_RELAXED, __HIP_MEMORY_SCOPE_AGENT);
  return __uint_as_float(u);
}
__device__ __forceinline__ void stf_c(float* p, float v) {
  __hip_atomic_store((unsigned*)p, __float_as_uint(v), __ATOMIC_RELAXED, __HIP_MEMORY_SCOPE_AGENT);
}

struct Params {
  const float *x, *W_ih, *b_ih, *W_hh, *Wq_in, *bq_in, *Wq, *bq, *Wk, *bk,
              *Wv, *bv, *Wo, *bo, *W_ac, *b_ac, *g_att, *be_att, *g_post, *be_post;
  float *out, *c, *q, *Qh, *ctx, *attp, *hv, *pre, *Kbuf, *Vbuf, *stA, *stP;
  unsigned *gen, *arr;
};

// Round-7 barrier: flag store + block-0 parallel aggregation + gen release.
__device__ __forceinline__ void gbar(unsigned* arr, unsigned* gen, unsigned g) {
  asm volatile("s_waitcnt vmcnt(0) lgkmcnt(0)" ::: "memory");
  __syncthreads();
  const int tid = threadIdx.x;
  if (tid == 0)
    __hip_atomic_store(&arr[blockIdx.x * FSTRIDE], g, __ATOMIC_RELAXED, __HIP_MEMORY_SCOPE_AGENT);
  if (blockIdx.x == 0) {
    if (tid < NBLK) {
      while (__hip_atomic_load(&arr[tid * FSTRIDE], __ATOMIC_RELAXED, __HIP_MEMORY_SCOPE_AGENT) < g)
        __builtin_amdgcn_s_sleep(1);
    }
    __syncthreads();
    if (tid == 0)
      __hip_atomic_store(gen, g, __ATOMIC_RELAXED, __HIP_MEMORY_SCOPE_AGENT);
  } else {
    if (tid == 0) {
      while (__hip_atomic_load(gen, __ATOMIC_RELAXED, __HIP_MEMORY_SCOPE_AGENT) < g)
        __builtin_amdgcn_s_sleep(1);
    }
  }
  __syncthreads();
}

// BN scale/shift from single-partial stats stP[2][512] (gates output).
__device__ __forceinline__ void prepP(const float* stP, const float* gn, const float* be,
                                      float* scl, float* shf, int tid) {
  if (tid < H_) {
    float S  = ldf_c(stP + tid);
    float S2 = ldf_c(stP + H_ + tid);
    float mu  = S * (1.f / B_);
    float var = S2 * (1.f / B_) - mu * mu;
    float sc  = rsqrtf(var + EPS_) * gn[tid];
    scl[tid] = sc; shf[tid] = be[tid] - mu * sc;
  }
}

// BN scale/shift from 4-way partial stats stA[4][2][512] (Wo GEMM output).
__device__ __forceinline__ void prepA(const float* stA, const float* gn, const float* be,
                                      float* scl, float* shf, int tid) {
  if (tid < H_) {
    float S  = ldf_c(stA + tid) + ldf_c(stA + 1024 + tid) + ldf_c(stA + 2048 + tid) + ldf_c(stA + 3072 + tid);
    float S2 = ldf_c(stA + 512 + tid) + ldf_c(stA + 1536 + tid) + ldf_c(stA + 2560 + tid) + ldf_c(stA + 3584 + tid);
    float mu  = S * (1.f / B_);
    float var = S2 * (1.f / B_) - mu * mu;
    float sc  = rsqrtf(var + EPS_) * gn[tid];
    scl[tid] = sc; shf[tid] = be[tid] - mu * sc;
  }
}

// ---------------------------------------------------------------------------
// 64x64 output tile, K-concat of up to 2 segments, 512 threads, 2x4 microtile.
// LDS double-buffered; ONE sync per 32-k slab. Prefetch: A depth-2, B depth-1,
// all as NAMED f4 values (no register arrays -> no scratch).
// ---------------------------------------------------------------------------
struct GJ {
  const float* A1; int lda1; int K1; int nrm1; int cg1;
  const float* A2; int lda2; int K2; int nrm2; int cg2;
  const float* W1; const float* W2;    // [K][N] row-major, stride N (plain)
  const float* b1; const float* b2; const float* addm;
  float* out; float* stats;
  int N; int m0; int n0; int doElu;
};

__device__ void gemm_tile(const GJ& J, int tid,
                          float (*As)[64][36], float (*Bs)[32][68],
                          const float* scl, const float* shf) {
  const int arow = tid >> 3, akq = (tid & 7) * 4;
  const int bkk = tid >> 4, bnn = (tid & 15) * 4;
  const int ty = tid >> 4, tx = tid & 15;

  float acc[2][4] = {{0.f,0.f,0.f,0.f},{0.f,0.f,0.f,0.f}};

  f4 am0 = {0.f,0.f,0.f,0.f}, am1 = {0.f,0.f,0.f,0.f};
  if (J.addm) {
    am0 = ld_c(J.addm + (size_t)(J.m0 + ty * 2)     * J.N + J.n0 + tx * 4);
    am1 = ld_c(J.addm + (size_t)(J.m0 + ty * 2 + 1) * J.N + J.n0 + tx * 4);
  }

  int buf = 0;
  for (int s = 0; s < 2; ++s) {
    const float* A = s ? J.A2 : J.A1;
    if (!A) break;
    const float* Wp  = s ? J.W2 : J.W1;
    const int K      = s ? J.K2 : J.K1;
    const int lda    = s ? J.lda2 : J.lda1;
    const int nrm    = s ? J.nrm2 : J.nrm1;
    const int cg     = s ? J.cg2 : J.cg1;
    const int nsl    = K >> 5;

    const float* aBase = A + (size_t)(J.m0 + arow) * lda + akq;
    const float* wBase = Wp + (size_t)bkk * J.N + J.n0 + bnn;
    const size_t wSlab = (size_t)32 * J.N;

    // prologue: named-value prefetch (depth 2 for A, 1 for B)
    f4 aN1 = cg ? ld_c(aBase) : *(const f4*)aBase;
    f4 aN2 = (nsl > 1) ? (cg ? ld_c(aBase + 32) : *(const f4*)(aBase + 32)) : aN1;
    f4 bN1 = *(const f4*)wBase;

    for (int sl = 0; sl < nsl; ++sl) {
      f4 aCur = aN1; aN1 = aN2;
      f4 bCur = bN1;
      if (sl + 2 < nsl) {
        const float* ap = aBase + (size_t)(sl + 2) * 32;
        aN2 = cg ? ld_c(ap) : *(const f4*)ap;
      }
      if (sl + 1 < nsl) bN1 = *(const f4*)(wBase + (size_t)(sl + 1) * wSlab);
      if (nrm) {
        #pragma unroll
        for (int i = 0; i < 4; ++i) {
          int gk = sl * 32 + akq + i;
          aCur[i] = aCur[i] * scl[gk] + shf[gk];
        }
      }
      *(f4*)&As[buf][arow][akq] = aCur;
      *(f4*)&Bs[buf][bkk][bnn] = bCur;
      __syncthreads();
      #pragma unroll
      for (int k = 0; k < 32; k += 2) {
        f2 a0 = *(const f2*)&As[buf][ty * 2][k];
        f2 a1 = *(const f2*)&As[buf][ty * 2 + 1][k];
        f4 b0 = *(const f4*)&Bs[buf][k][tx * 4];
        f4 b1 = *(const f4*)&Bs[buf][k + 1][tx * 4];
        #pragma unroll
        for (int j = 0; j < 4; ++j) {
          acc[0][j] = fmaf(a0[0], b0[j], acc[0][j]);
          acc[0][j] = fmaf(a0[1], b1[j], acc[0][j]);
          acc[1][j] = fmaf(a1[0], b0[j], acc[1][j]);
          acc[1][j] = fmaf(a1[1], b1[j], acc[1][j]);
        }
      }
      buf ^= 1;
    }
  }

  const int r0 = J.m0 + ty * 2, c0 = J.n0 + tx * 4;
  f4 bias = {0.f, 0.f, 0.f, 0.f};
  if (J.b1) bias += *(const f4*)(J.b1 + c0);
  if (J.b2) bias += *(const f4*)(J.b2 + c0);
  f4 v0, v1;
  #pragma unroll
  for (int j = 0; j < 4; ++j) { v0[j] = acc[0][j] + bias[j]; v1[j] = acc[1][j] + bias[j]; }
  if (J.addm) { v0 += am0; v1 += am1; }
  if (J.doElu) {
    #pragma unroll
    for (int j = 0; j < 4; ++j) { v0[j] = eluf(v0[j]); v1[j] = eluf(v1[j]); }
  }
  st_c(J.out + (size_t)r0 * J.N + c0, v0);
  st_c(J.out + (size_t)(r0 + 1) * J.N + c0, v1);

  if (J.stats) {   // deterministic per-64-row-tile column partials
    float* Af = (float*)As;
    float* Bf = (float*)Bs;
    __syncthreads();
    #pragma unroll
    for (int j = 0; j < 4; ++j) {
      Af[ty * 64 + tx * 4 + j] = v0[j] + v1[j];
      Bf[ty * 64 + tx * 4 + j] = v0[j] * v0[j] + v1[j] * v1[j];
    }
    __syncthreads();
    if (tid < 64) {
      float S = 0.f, S2 = 0.f;
      #pragma unroll
      for (int y = 0; y < 32; ++y) { S += Af[y * 64 + tid]; S2 += Bf[y * 64 + tid]; }
      const int tm = J.m0 >> 6;
      stf_c(J.stats + tm * 1024 + J.n0 + tid, S);
      stf_c(J.stats + tm * 1024 + 512 + J.n0 + tid, S2);
    }
  }
}

__global__ __launch_bounds__(NTHR, 1) void larnn(Params P) {
  __shared__ float As[2][64][36];
  __shared__ float Bs[2][32][68];
  __shared__ float scl[H_], shf[H_];
  __shared__ float Qs[H_];
  __shared__ float sc_[8][16], aw_[8][16];

  const int bid = blockIdx.x, tid = threadIdx.x;
  unsigned g = 0;

  for (int t = 0; t < T_; ++t) {
    const float* xt = P.x + (size_t)t * B_ * F_;
    const int slot = (t - 1) & 15;

    // =========== P1: q | K-ring | V-ring | preA | out[t-1] ===========
    if (bid < 32) {
      if (t > 0) { prepP(P.stP, P.g_post, P.be_post, scl, shf, tid); __syncthreads(); }
      GJ J = {}; J.A1 = xt; J.lda1 = F_; J.K1 = F_;
      if (t > 0) { J.A2 = P.hv; J.lda2 = H_; J.K2 = H_; J.nrm2 = 1; J.cg2 = 1; }
      J.W1 = P.Wq_in; J.W2 = P.Wq_in + (size_t)F_ * H_;
      J.b1 = P.bq_in; J.out = P.q; J.N = H_;
      J.m0 = (bid >> 3) * 64; J.n0 = (bid & 7) * 64; J.doElu = 1;
      gemm_tile(J, tid, As, Bs, scl, shf);
    } else if (bid < 64) {
      int l = bid - 32;
      GJ J = {}; J.A1 = P.c; J.lda1 = H_; J.K1 = H_; J.cg1 = 1;
      J.W1 = P.Wk; J.b1 = P.bk; J.out = P.Kbuf + (size_t)slot * BH_; J.N = H_;
      J.m0 = (l >> 3) * 64; J.n0 = (l & 7) * 64; J.doElu = 1;
      gemm_tile(J, tid, As, Bs, scl, shf);
    } else if (bid < 96) {
      int l = bid - 64;
      GJ J = {}; J.A1 = P.c; J.lda1 = H_; J.K1 = H_; J.cg1 = 1;
      J.W1 = P.Wv; J.b1 = P.bv; J.out = P.Vbuf + (size_t)slot * BH_; J.N = H_;
      J.m0 = (l >> 3) * 64; J.n0 = (l & 7) * 64; J.doElu = 1;
      gemm_tile(J, tid, As, Bs, scl, shf);
    } else if (bid < 224) {
      if (t > 0) { prepP(P.stP, P.g_post, P.be_post, scl, shf, tid); __syncthreads(); }
      const int ix = bid - 96;
      GJ J = {}; J.A1 = xt; J.lda1 = F_; J.K1 = F_;
      if (t > 0) { J.A2 = P.hv; J.lda2 = H_; J.K2 = H_; J.nrm2 = 1; J.cg2 = 1; }
      J.W1 = P.W_ih; J.W2 = P.W_hh;
      J.b1 = P.b_ih; J.b2 = P.b_ac; J.out = P.pre; J.N = H4_;
      J.m0 = (ix >> 5) * 64; J.n0 = (ix & 31) * 64;
      gemm_tile(J, tid, As, Bs, scl, shf);
    } else if (t > 0) {
      prepP(P.stP, P.g_post, P.be_post, scl, shf, tid);
      __syncthreads();
      const int rb0 = (bid - 224) * 8;
      for (int idx = tid; idx < 1024; idx += NTHR) {
        int r = rb0 + (idx >> 7), cc = (idx & 127) * 4;
        f4 hvv = ld_c(P.hv + (size_t)r * H_ + cc);
        f4 v;
        #pragma unroll
        for (int i = 0; i < 4; ++i) v[i] = hvv[i] * scl[cc + i] + shf[cc + i];
        *(f4*)(P.out + (size_t)(t - 1) * BH_ + (size_t)r * H_ + cc) = v;
      }
    }
    gbar(P.arr, P.gen, ++g);

    // =========== P2: Qh = q@Wq + bq ===========
    if (bid < 32) {
      GJ J = {}; J.A1 = P.q; J.lda1 = H_; J.K1 = H_; J.cg1 = 1;
      J.W1 = P.Wq; J.b1 = P.bq; J.out = P.Qh; J.N = H_;
      J.m0 = (bid >> 3) * 64; J.n0 = (bid & 7) * 64;
      gemm_tile(J, tid, As, Bs, scl, shf);
    }
    gbar(P.arr, P.gen, ++g);

    // =========== P3: attention (1 batch row / block) ===========
    {
      const int b = bid;
      const int nv = (t + 1 < W_) ? t + 1 : W_;
      if (tid < 128) *(f4*)&Qs[tid * 4] = ld_c(P.Qh + (size_t)b * H_ + tid * 4);
      __syncthreads();
      {
        const int p = tid >> 2, l4 = tid & 3;
        const int hh = p >> 4, w = p & 15;
        if (w < nv) {
          const int sl = (t - 1 - w) & 15;
          const float* kp = P.Kbuf + ((size_t)sl * B_ + b) * H_ + hh * 64 + l4 * 16;
          const float* qp = Qs + hh * 64 + l4 * 16;
          float s = 0.f;
          #pragma unroll
          for (int d = 0; d < 16; d += 4) {
            f4 kv = ld_c(kp + d);
            f4 qv = *(const f4*)(qp + d);
            s = fmaf(kv[0], qv[0], fmaf(kv[1], qv[1], fmaf(kv[2], qv[2], fmaf(kv[3], qv[3], s))));
          }
          s += __shfl_xor(s, 1); s += __shfl_xor(s, 2);
          if (l4 == 0) sc_[hh][w] = s * 0.125f;
        }
      }
      __syncthreads();
      if (tid < 8) {
        float mx = -1e30f;
        for (int w = 0; w < nv; ++w) mx = fmaxf(mx, sc_[tid][w]);
        float ss = 0.f;
        for (int w = 0; w < nv; ++w) { float e = expf(sc_[tid][w] - mx); aw_[tid][w] = e; ss += e; }
        float inv = 1.f / ss;
        for (int w = 0; w < nv; ++w) aw_[tid][w] *= inv;
      }
      __syncthreads();
      {
        const int j = tid, hh = j >> 6;
        float o = 0.f;
        for (int w = 0; w < nv; ++w) {
          const int sl = (t - 1 - w) & 15;
          o = fmaf(aw_[hh][w], ldf_c(P.Vbuf + ((size_t)sl * B_ + b) * H_ + j), o);
        }
        stf_c(P.ctx + (size_t)b * H_ + j, o);
      }
    }
    gbar(P.arr, P.gen, ++g);

    // =========== P4: attp = elu(ctx@Wo + bo) + BN partials ===========
    if (bid < 32) {
      GJ J = {}; J.A1 = P.ctx; J.lda1 = H_; J.K1 = H_; J.cg1 = 1;
      J.W1 = P.Wo; J.b1 = P.bo; J.doElu = 1;
      J.out = P.attp; J.stats = P.stA; J.N = H_;
      J.m0 = (bid >> 3) * 64; J.n0 = (bid & 7) * 64;
      gemm_tile(J, tid, As, Bs, scl, shf);
    }
    gbar(P.arr, P.gen, ++g);

    // =========== P5: pre += BN(attp)@W_ac ===========
    if (bid < 128) {
      prepA(P.stA, P.g_att, P.be_att, scl, shf, tid);
      __syncthreads();
      GJ J = {}; J.A1 = P.attp; J.lda1 = H_; J.K1 = H_; J.cg1 = 1; J.nrm1 = 1;
      J.W1 = P.W_ac; J.addm = P.pre; J.out = P.pre; J.N = H4_;
      J.m0 = (bid >> 5) * 64; J.n0 = (bid & 31) * 64;
      gemm_tile(J, tid, As, Bs, scl, shf);
    }
    gbar(P.arr, P.gen, ++g);

    // =========== P6: gates + c/hv + BN-post stats ===========
    if (bid < 64) {
      f4* rS = (f4*)As;
      f4* rQ = (f4*)Bs;
      const int sub = tid & 1, r = tid >> 1;
      const int c4 = bid * 8 + sub * 4;
      const size_t rb = (size_t)r * H4_;
      f4 p0 = ld_c(P.pre + rb + c4);
      f4 pf = ld_c(P.pre + rb + c4 + 512);
      f4 pi = ld_c(P.pre + rb + c4 + 1024);
      f4 po = ld_c(P.pre + rb + c4 + 1536);
      const size_t ci = (size_t)r * H_ + c4;
      f4 cold = ld_c(P.c + ci);
      f4 cn, hvv;
      #pragma unroll
      for (int i = 0; i < 4; ++i) {
        float iv = tanhf(p0[i]);
        float fg = sigf(pf[i]), ig = sigf(pi[i]), og = sigf(po[i]);
        cn[i] = iv * ig + cold[i] * fg;
        hvv[i] = og * eluf(cn[i]);
      }
      st_c(P.c + ci, cn);
      st_c(P.hv + ci, hvv);
      rS[sub * 256 + r] = hvv;
      rQ[sub * 256 + r] = hvv * hvv;
      __syncthreads();
      for (int s2 = 128; s2 > 0; s2 >>= 1) {
        if (r < s2) {
          rS[sub * 256 + r] += rS[sub * 256 + r + s2];
          rQ[sub * 256 + r] += rQ[sub * 256 + r + s2];
        }
        __syncthreads();
      }
      if (r == 0) {
        f4 S = rS[sub * 256], Q2 = rQ[sub * 256];
        #pragma unroll
        for (int i = 0; i < 4; ++i) { stf_c(P.stP + c4 + i, S[i]); stf_c(P.stP + 512 + c4 + i, Q2[i]); }
      }
    }
    gbar(P.arr, P.gen, ++g);
  }

  // =========== final out-copy for t = 127 ===========
  if (bid >= 224) {
    prepP(P.stP, P.g_post, P.be_post, scl, shf, tid);
    __syncthreads();
    const int rb0 = (bid - 224) * 8;
    for (int idx = tid; idx < 1024; idx += NTHR) {
      int r = rb0 + (idx >> 7), cc = (idx & 127) * 4;
      f4 hvv = ld_c(P.hv + (size_t)r * H_ + cc);
      f4 v;
      #pragma unroll
      for (int i = 0; i < 4; ++i) v[i] = hvv[i] * scl[cc + i] + shf[cc + i];
      *(f4*)(P.out + (size_t)127 * BH_ + (size_t)r * H_ + cc) = v;
    }
  }
}

#define SYNC_UINTS (32 + NBLK * FSTRIDE)   // gen line + 256 padded flags

__global__ __launch_bounds__(256) void pinit(float* c, unsigned* sync) {
  const int i = blockIdx.x * 256 + threadIdx.x;
  if (i < BH_) c[i] = 0.f;
  if (i < SYNC_UINTS) sync[i] = 0u;
}

extern "C" void kernel_launch(void* const* d_in, const int* in_sizes, int n_in,
                              void* d_out, int out_size, void* d_ws, size_t ws_size,
                              hipStream_t stream) {
  Params P;
  P.x      = (const float*)d_in[0];
  P.W_ih   = (const float*)d_in[1];
  P.b_ih   = (const float*)d_in[2];
  P.W_hh   = (const float*)d_in[3];
  P.Wq_in  = (const float*)d_in[4];
  P.bq_in  = (const float*)d_in[5];
  P.Wq     = (const float*)d_in[6];
  P.bq     = (const float*)d_in[7];
  P.Wk     = (const float*)d_in[8];
  P.bk     = (const float*)d_in[9];
  P.Wv     = (const float*)d_in[10];
  P.bv     = (const float*)d_in[11];
  P.Wo     = (const float*)d_in[12];
  P.bo     = (const float*)d_in[13];
  P.W_ac   = (const float*)d_in[14];
  P.b_ac   = (const float*)d_in[15];
  P.g_att  = (const float*)d_in[16];
  P.be_att = (const float*)d_in[17];
  P.g_post = (const float*)d_in[18];
  P.be_post= (const float*)d_in[19];
  P.out    = (float*)d_out;

  unsigned* sync = (unsigned*)d_ws;
  P.gen = sync;                    // own 128B line
  P.arr = sync + 32;               // 256 flags, 128B stride
  float* fb = (float*)d_ws + SYNC_UINTS;
  P.c    = fb;                 fb += BH_;
  P.q    = fb;                 fb += BH_;
  P.Qh   = fb;                 fb += BH_;
  P.ctx  = fb;                 fb += BH_;
  P.attp = fb;                 fb += BH_;
  P.hv   = fb;                 fb += BH_;
  P.pre  = fb;                 fb += (size_t)B_ * H4_;
  P.Kbuf = fb;                 fb += (size_t)W_ * BH_;
  P.Vbuf = fb;                 fb += (size_t)W_ * BH_;
  P.stA  = fb;                 fb += 4096;
  P.stP  = fb;                 fb += 1024;

  pinit<<<(BH_ + 255) / 256, 256, 0, stream>>>(P.c, sync);
  larnn<<<NBLK, NTHR, 0, stream>>>(P);
}